// Round 3
// baseline (251.508 us; speedup 1.0000x reference)
//
#include <hip/hip_runtime.h>

// out[b,s,d] = alpha*sum_{j=1..P} beta^{j-1} x[b,s-j,d] + pf[d] + pb[((s>>5)-d)&31]
//
// EXACTLY-RESIDENT PIPELINED READ-ONCE. R2 (grid 256, ROWS=4) pipelined but had
// 1 block/CU = 8 waves: scans + store-drains exposed, latency-bound (112 us,
// 1.79 TB/s). R1 (grid 1024, 1 row) had 92 VGPR -> only 2 blocks/CU resident ->
// TWO sequential block rounds with retire/relaunch seams (80 us). This version:
// grid = 512 = exactly 2 blocks/CU (whole grid resident, zero seams), ROWS=2 with
// R2's row pipelining (next-row loads issued before current pass A, raw s_barrier +
// lgkmcnt-only waits keep them in flight across both barriers). The co-resident
// second block covers each block's scan/store phases. Scan loop unrolled so its
// ds_reads pipeline (carried dep = 64-fma chain only). NT stores kept: they leave
// x LLC-resident across iterations (R2 measured FETCH_SIZE halved to 65.6 MB).
// Numerics bit-identical to R0/R1/R2 (same FMA order, same shfl lag).

typedef float f32x4 __attribute__((ext_vector_type(4)));

constexpr int S    = 1024;
constexpr int D    = 32;
constexpr int CL   = 16;              // 16-runs stay inside one 32-block => s>>5 const
constexpr int NCH  = S / CL;          // 64 chunks
constexpr int LAG  = 8;               // P / CL
constexpr int NTHR = NCH * (D / 4);   // 512
constexpr int ROWS = 2;               // batch rows per block (pipeline depth)

__global__ __launch_bounds__(NTHR, 4)
void attn_pred_kernel(const float* __restrict__ x,
                      const float* __restrict__ alpha_p,
                      const float* __restrict__ beta_p,
                      const float* __restrict__ pos_fwd,
                      const float* __restrict__ pos_bwd,
                      const int*   __restrict__ past_p,
                      float* __restrict__ out, int B)
{
    __shared__ f32x4 sA[NCH][D / 4];  // 4 KiB: pure chunk sums
    __shared__ f32x4 sC[NCH][D / 4];  // 4 KiB: exclusive carries

    const int tid  = threadIdx.x;
    const int lane = tid & 63;
    const int wv   = tid >> 6;        // wave 0..7
    const int g    = lane >> 3;       // lag-group 0..7 within wave
    const int dg   = lane & 7;        // float4 group over d
    const int c    = g * 8 + wv;      // chunk 0..63; chunk c-LAG == lane-8, same wave
    const int s0   = c * CL;

    const float alpha = alpha_p[0];
    const float beta  = beta_p[0];
    const int   P     = past_p[0];    // 128

    // beta^P by squaring (double), beta^CL by 4 squarings
    double bb = (double)beta, bpd = 1.0;
    for (int e = P; e; e >>= 1) { if (e & 1) bpd *= bb; bb *= bb; }
    const float bP = (float)bpd;
    double b16 = (double)beta;
    for (int i = 0; i < 4; ++i) b16 *= b16;
    const float bCL = (float)b16;     // beta^16
    const float aP  = alpha * bP;     // alpha*beta^P
    const float m   = (g > 0) ? -aP : 0.f;  // lanes 0..7: shfl_up returns own value, killed

    // positional bias (s>>5 == c>>1, constant over the chunk) — row-independent
    const int d0 = dg * 4;
    const int q  = c >> 1;
    const f32x4 pf = reinterpret_cast<const f32x4*>(pos_fwd)[dg];
    f32x4 add;
    add.x = pf.x + pos_bwd[(q - (d0 + 0)) & (D - 1)];
    add.y = pf.y + pos_bwd[(q - (d0 + 1)) & (D - 1)];
    add.z = pf.z + pos_bwd[(q - (d0 + 2)) & (D - 1)];
    add.w = pf.w + pos_bwd[(q - (d0 + 3)) & (D - 1)];

    const size_t rowStride = (size_t)S * (D / 4);
    const int    b0        = blockIdx.x * ROWS;
    const f32x4* xg0 = reinterpret_cast<const f32x4*>(x)
                       + (size_t)b0 * rowStride + dg;
    f32x4*       og0 = reinterpret_cast<f32x4*>(out)
                       + (size_t)b0 * rowStride + (size_t)s0 * (D / 4) + dg;

    f32x4 xra[CL], xrb[CL];           // ping-pong row buffers (64+64 VGPR)

    // prologue: load row 0 (b0 < B guaranteed by grid sizing)
    #pragma unroll
    for (int i = 0; i < CL; ++i)
        xra[i] = xg0[(s0 + i) * (D / 4)];

// Row body. XR = current row's regs, XN = next row's regs, R = compile-time row idx.
// Macro (not pointer swap) so every register-array index is compile-time constant.
#define ROW_BODY(XR, XN, R)                                                      \
  if (b0 + (R) < B) {                                                            \
    /* issue next row's loads FIRST: they stream under everything below */       \
    if (((R) + 1 < ROWS) && (b0 + (R) + 1 < B)) {                                \
      const f32x4* xgn = xg0 + ((R) + 1) * rowStride;                            \
      _Pragma("unroll")                                                          \
      for (int i = 0; i < CL; ++i) XN[i] = xgn[(s0 + i) * (D / 4)];              \
    }                                                                            \
    /* pass A: decayed chunk sum from registers (waits only XR's vmcnt) */       \
    f32x4 A = {0.f, 0.f, 0.f, 0.f};                                              \
    _Pragma("unroll")                                                            \
    for (int i = 0; i < CL; ++i) {                                               \
      A.x = fmaf(beta, A.x, XR[i].x);                                            \
      A.y = fmaf(beta, A.y, XR[i].y);                                            \
      A.z = fmaf(beta, A.z, XR[i].z);                                            \
      A.w = fmaf(beta, A.w, XR[i].w);                                            \
    }                                                                            \
    sA[c][dg] = A;                                                               \
    asm volatile("s_waitcnt lgkmcnt(0)" ::: "memory"); /* LDS only — loads fly */\
    __builtin_amdgcn_s_barrier();                                                \
    __builtin_amdgcn_sched_barrier(0);                                           \
    /* scan (8 threads): exclusive carries over 64 chunks; unrolled so ds_reads  \
       pipeline and the carried dep is just the fma chain */                     \
    if (tid < D / 4) {                                                           \
      f32x4 run = {0.f, 0.f, 0.f, 0.f};                                          \
      _Pragma("unroll")                                                          \
      for (int cc = 0; cc < NCH; ++cc) {                                         \
        sC[cc][tid] = run;                                                       \
        const f32x4 Ac = sA[cc][tid];                                            \
        f32x4 z;                                                                 \
        if (cc >= LAG) {                                                         \
          const f32x4 Al = sA[cc - LAG][tid];                                    \
          z.x = alpha * fmaf(-bP, Al.x, Ac.x);                                   \
          z.y = alpha * fmaf(-bP, Al.y, Ac.y);                                   \
          z.z = alpha * fmaf(-bP, Al.z, Ac.z);                                   \
          z.w = alpha * fmaf(-bP, Al.w, Ac.w);                                   \
        } else {                                                                 \
          z.x = alpha * Ac.x; z.y = alpha * Ac.y;                                \
          z.z = alpha * Ac.z; z.w = alpha * Ac.w;                                \
        }                                                                        \
        run.x = fmaf(bCL, run.x, z.x);                                           \
        run.y = fmaf(bCL, run.y, z.y);                                           \
        run.z = fmaf(bCL, run.z, z.z);                                           \
        run.w = fmaf(bCL, run.w, z.w);                                           \
      }                                                                          \
    }                                                                            \
    asm volatile("s_waitcnt lgkmcnt(0)" ::: "memory");                           \
    __builtin_amdgcn_s_barrier();                                                \
    __builtin_amdgcn_sched_barrier(0);                                           \
    f32x4 y = sC[c][dg];                                                         \
    /* pass B: emit 16 outputs; lagged x via intra-wave shuffle (read-once) */   \
    f32x4* og = og0 + (R) * rowStride;                                           \
    _Pragma("unroll")                                                            \
    for (int i = 0; i < CL; ++i) {                                               \
      f32x4 o;                                                                   \
      o.x = y.x + add.x; o.y = y.y + add.y;                                      \
      o.z = y.z + add.z; o.w = y.w + add.w;                                      \
      __builtin_nontemporal_store(o, &og[i * (D / 4)]);                          \
      f32x4 xl;                                                                  \
      xl.x = __shfl_up(XR[i].x, 8);                                              \
      xl.y = __shfl_up(XR[i].y, 8);                                              \
      xl.z = __shfl_up(XR[i].z, 8);                                              \
      xl.w = __shfl_up(XR[i].w, 8);                                              \
      y.x = fmaf(beta, y.x, fmaf(alpha, XR[i].x, m * xl.x));                     \
      y.y = fmaf(beta, y.y, fmaf(alpha, XR[i].y, m * xl.y));                     \
      y.z = fmaf(beta, y.z, fmaf(alpha, XR[i].z, m * xl.z));                     \
      y.w = fmaf(beta, y.w, fmaf(alpha, XR[i].w, m * xl.w));                     \
    }                                                                            \
  }

    ROW_BODY(xra, xrb, 0)
    ROW_BODY(xrb, xra, 1)
#undef ROW_BODY
}

extern "C" void kernel_launch(void* const* d_in, const int* in_sizes, int n_in,
                              void* d_out, int out_size, void* d_ws, size_t ws_size,
                              hipStream_t stream) {
    const float* x  = (const float*)d_in[0];
    const float* al = (const float*)d_in[1];
    const float* be = (const float*)d_in[2];
    const float* pf = (const float*)d_in[3];
    const float* pb = (const float*)d_in[4];
    const int*   ps = (const int*)d_in[5];
    float* out = (float*)d_out;

    const int B = in_sizes[0] / (S * D);   // 1024
    const int grid = (B + ROWS - 1) / ROWS; // 512 -> exactly 2 blocks per CU
    attn_pred_kernel<<<dim3(grid), NTHR, 0, stream>>>(x, al, be, pf, pb, ps, out, B);
}

// Round 4
// 246.907 us; speedup vs baseline: 1.0186x; 1.0186x over previous
//
#include <hip/hip_runtime.h>

// out[b,s,d] = alpha*sum_{j=1..P} beta^{j-1} x[b,s-j,d] + pf[d] + pb[((s>>5)-d)&31]
//
// MAX-OCCUPANCY READ-ONCE. Cross-round counter analysis: memory-system throughput
// (HBM+LLC bytes/time) scales with resident waves, not bytes — R0: 5.7 TB/s @ ~21
// waves/CU (read-3x), R1: 3.35 @ 16, R2: 1.8 @ 8. Concurrency-bound, not bytes-
// bound. R3's reg ping-pong spilled to scratch (VGPR=64 + WRITE_SIZE 216 MB = spill
// traffic). This version keeps read-once + shfl-lag but halves the per-thread
// payload: CL=8 -> xr[8] = 32 VGPR data, ~55 total -> __launch_bounds__(1024,8)
// gives 2x 1024-thread blocks per CU = 32 waves/CU (chip max). Block = one row,
// 128 chunks x 8 dg. LAG = P/CL = 16 chunks; mapping c = g*16 + wv puts chunk c-16
// exactly 8 lanes down in the same wave -> same shfl_up(8) lag, zero re-reads.
// Serial scan becomes 128 iters (still negligible: VALUBusy <6% all rounds).
// Plain __syncthreads() (no cross-phase loads to protect). NT stores kept: R2
// measured they keep x LLC-resident (FETCH_SIZE halved).

typedef float f32x4 __attribute__((ext_vector_type(4)));

constexpr int S    = 1024;
constexpr int D    = 32;
constexpr int CL   = 8;               // chunk length (8 stays inside one 32-block)
constexpr int NCH  = S / CL;          // 128 chunks
constexpr int LAG  = 16;              // P / CL
constexpr int NTHR = NCH * (D / 4);   // 1024 threads = 16 waves

__global__ __launch_bounds__(NTHR, 8)   // 8 waves/EU min => VGPR<=64 => 2 blocks/CU
void attn_pred_kernel(const float* __restrict__ x,
                      const float* __restrict__ alpha_p,
                      const float* __restrict__ beta_p,
                      const float* __restrict__ pos_fwd,
                      const float* __restrict__ pos_bwd,
                      const int*   __restrict__ past_p,
                      float* __restrict__ out)
{
    __shared__ f32x4 sA[NCH][D / 4];  // 16 KiB: pure chunk sums
    __shared__ f32x4 sC[NCH][D / 4];  // 16 KiB: exclusive carries

    const int tid  = threadIdx.x;
    const int b    = blockIdx.x;
    const int lane = tid & 63;
    const int wv   = tid >> 6;        // wave 0..15
    const int g    = lane >> 3;       // lag-group 0..7 within wave
    const int dg   = lane & 7;        // float4 group over d
    const int c    = g * 16 + wv;     // chunk 0..127; chunk c-LAG == lane-8, same wave
    const int s0   = c * CL;

    const float alpha = alpha_p[0];
    const float beta  = beta_p[0];
    const int   P     = past_p[0];    // 128

    // beta^P by squaring (double), beta^CL by 3 squarings
    double bb = (double)beta, bpd = 1.0;
    for (int e = P; e; e >>= 1) { if (e & 1) bpd *= bb; bb *= bb; }
    const float bP = (float)bpd;
    double b8d = (double)beta;
    for (int i = 0; i < 3; ++i) b8d *= b8d;
    const float bCL = (float)b8d;     // beta^8
    const float aP  = alpha * bP;     // alpha*beta^P
    const float m   = (g > 0) ? -aP : 0.f;  // c<LAG <=> g==0: lag term killed

    // positional bias: s>>5 constant over an 8-chunk (s0=c*8 -> s>>5 == c>>2)
    const int d0 = dg * 4;
    const int q  = c >> 2;
    const f32x4 pf = reinterpret_cast<const f32x4*>(pos_fwd)[dg];
    f32x4 add;
    add.x = pf.x + pos_bwd[(q - (d0 + 0)) & (D - 1)];
    add.y = pf.y + pos_bwd[(q - (d0 + 1)) & (D - 1)];
    add.z = pf.z + pos_bwd[(q - (d0 + 2)) & (D - 1)];
    add.w = pf.w + pos_bwd[(q - (d0 + 3)) & (D - 1)];

    const f32x4* xg = reinterpret_cast<const f32x4*>(x) + (size_t)b * S * (D / 4) + dg;

    // ---- pass A: load chunk ONCE into registers; decayed chunk sum ----
    f32x4 xr[CL];                     // 32 VGPRs, statically indexed
    #pragma unroll
    for (int i = 0; i < CL; ++i)
        xr[i] = xg[(s0 + i) * (D / 4)];

    f32x4 A = {0.f, 0.f, 0.f, 0.f};
    #pragma unroll
    for (int i = 0; i < CL; ++i) {
        A.x = fmaf(beta, A.x, xr[i].x);
        A.y = fmaf(beta, A.y, xr[i].y);
        A.z = fmaf(beta, A.z, xr[i].z);
        A.w = fmaf(beta, A.w, xr[i].w);
    }
    sA[c][dg] = A;
    __syncthreads();

    // ---- scan (8 threads, one per dg): exclusive carries over 128 chunks ----
    if (tid < D / 4) {
        f32x4 run = {0.f, 0.f, 0.f, 0.f};
        #pragma unroll 8
        for (int cc = 0; cc < NCH; ++cc) {
            sC[cc][tid] = run;
            const f32x4 Ac = sA[cc][tid];
            f32x4 z;
            if (cc >= LAG) {
                const f32x4 Al = sA[cc - LAG][tid];
                z.x = alpha * fmaf(-bP, Al.x, Ac.x);
                z.y = alpha * fmaf(-bP, Al.y, Ac.y);
                z.z = alpha * fmaf(-bP, Al.z, Ac.z);
                z.w = alpha * fmaf(-bP, Al.w, Ac.w);
            } else {
                z.x = alpha * Ac.x; z.y = alpha * Ac.y;
                z.z = alpha * Ac.z; z.w = alpha * Ac.w;
            }
            run.x = fmaf(bCL, run.x, z.x);
            run.y = fmaf(bCL, run.y, z.y);
            run.z = fmaf(bCL, run.z, z.z);
            run.w = fmaf(bCL, run.w, z.w);
        }
    }
    __syncthreads();
    f32x4 y = sC[c][dg];

    // ---- pass B: emit 8 outputs; lagged x via intra-wave shuffle (read-once) ----
    f32x4* og = reinterpret_cast<f32x4*>(out) + ((size_t)b * S + s0) * (D / 4) + dg;
    #pragma unroll
    for (int i = 0; i < CL; ++i) {
        f32x4 o;
        o.x = y.x + add.x; o.y = y.y + add.y;
        o.z = y.z + add.z; o.w = y.w + add.w;
        __builtin_nontemporal_store(o, &og[i * (D / 4)]);

        f32x4 xl;
        xl.x = __shfl_up(xr[i].x, 8);
        xl.y = __shfl_up(xr[i].y, 8);
        xl.z = __shfl_up(xr[i].z, 8);
        xl.w = __shfl_up(xr[i].w, 8);

        y.x = fmaf(beta, y.x, fmaf(alpha, xr[i].x, m * xl.x));
        y.y = fmaf(beta, y.y, fmaf(alpha, xr[i].y, m * xl.y));
        y.z = fmaf(beta, y.z, fmaf(alpha, xr[i].z, m * xl.z));
        y.w = fmaf(beta, y.w, fmaf(alpha, xr[i].w, m * xl.w));
    }
}

extern "C" void kernel_launch(void* const* d_in, const int* in_sizes, int n_in,
                              void* d_out, int out_size, void* d_ws, size_t ws_size,
                              hipStream_t stream) {
    const float* x  = (const float*)d_in[0];
    const float* al = (const float*)d_in[1];
    const float* be = (const float*)d_in[2];
    const float* pf = (const float*)d_in[3];
    const float* pb = (const float*)d_in[4];
    const int*   ps = (const int*)d_in[5];
    float* out = (float*)d_out;

    const int B = in_sizes[0] / (S * D);   // 1024 rows, one block each
    attn_pred_kernel<<<dim3(B), NTHR, 0, stream>>>(x, al, be, pf, pb, ps, out);
}

// Round 5
// 244.737 us; speedup vs baseline: 1.0277x; 1.0089x over previous
//
#include <hip/hip_runtime.h>

// out[b,s,d] = alpha*sum_{j=1..P} beta^{j-1} x[b,s-j,d] + pf[d] + pb[((s>>5)-d)&31]
//
// R0-STRUCTURE + SHFL-LAG + HALF-KEEP. Cross-round law: system BW ~ (waves/CU) x
// (fraction of wave lifetime memory-active). R0 (512thr, CL=16, VGPR 24, 4 indep
// blocks/CU, loads spread through pass B) = 5.3 TB/s system; R4 (2x16-wave blocks,
// loads only in first 5% of block life) = 3.1 TB/s at the SAME 32 waves/CU. So:
// return to R0's 4-blocks/CU regime and cut its redundant bytes without crossing
// the 64-VGPR cliff (8 waves/EU):
//  1) lag stream via shuffle (FREE): chunks remapped c = g*8+wv so chunk c-8 is
//     8 lanes down; in pass B all lanes hold xt_i in lockstep -> xl_i =
//     shfl_up(xt_i, 8). Deletes R0's 117 MB xl read stream, zero VGPR cost.
//  2) half-keep: xr[8] (32 VGPR) retains the chunk's first 8 float4 from pass A;
//     pass B iters 0-7 run from regs (no post-barrier stall), iters 8-15 re-read
//     x from LLC (x stays LLC-resident because NT stores don't evict it -- R2/R4
//     measured FETCH_SIZE = 65 MB, half of x). Total ~56-60 VGPR, under the cliff
//     (R1's full-keep was 92 -> 2 blocks/CU; R3's ping-pong spilled).
// System traffic 335 MB (vs R0's 504) at R0's demonstrated >=5.3 TB/s.
// Numerics: identical FMA order to R0/R1 (both passed, absmax 0.03125); shuffled
// xl carries the same bits the re-read had.

typedef float f32x4 __attribute__((ext_vector_type(4)));

constexpr int S    = 1024;
constexpr int D    = 32;
constexpr int CL   = 16;              // 16-runs stay inside one 32-block => s>>5 const
constexpr int NCH  = S / CL;          // 64 chunks
constexpr int LAG  = 8;               // P / CL
constexpr int KEEP = 8;               // first half of chunk kept in registers
constexpr int NTHR = NCH * (D / 4);   // 512 threads = 8 waves

__global__ __launch_bounds__(NTHR, 8)   // force VGPR<=64 => 4 blocks/CU = 32 waves
void attn_pred_kernel(const float* __restrict__ x,
                      const float* __restrict__ alpha_p,
                      const float* __restrict__ beta_p,
                      const float* __restrict__ pos_fwd,
                      const float* __restrict__ pos_bwd,
                      const int*   __restrict__ past_p,
                      float* __restrict__ out)
{
    __shared__ f32x4 sA[NCH][D / 4];  // 4 KiB: pure chunk sums
    __shared__ f32x4 sC[NCH][D / 4];  // 4 KiB: exclusive carries

    const int tid  = threadIdx.x;
    const int b    = blockIdx.x;
    const int lane = tid & 63;
    const int wv   = tid >> 6;        // wave 0..7
    const int g    = lane >> 3;       // lag-group 0..7 within wave
    const int dg   = lane & 7;        // float4 group over d
    const int c    = g * 8 + wv;      // chunk 0..63; chunk c-LAG == lane-8, same wave
    const int s0   = c * CL;

    const float alpha = alpha_p[0];
    const float beta  = beta_p[0];
    const int   P     = past_p[0];    // 128

    // beta^P by squaring (double), beta^CL by 4 squarings
    double bb = (double)beta, bpd = 1.0;
    for (int e = P; e; e >>= 1) { if (e & 1) bpd *= bb; bb *= bb; }
    const float bP = (float)bpd;
    double b16 = (double)beta;
    for (int i = 0; i < 4; ++i) b16 *= b16;
    const float bCL = (float)b16;     // beta^16
    const float aP  = alpha * bP;     // alpha*beta^P
    const float m   = (g > 0) ? -aP : 0.f;  // c<LAG <=> g==0: lag term killed

    // positional bias (s>>5 == c>>1, constant over the chunk)
    const int d0 = dg * 4;
    const int q  = c >> 1;
    const f32x4 pf = reinterpret_cast<const f32x4*>(pos_fwd)[dg];
    f32x4 add;
    add.x = pf.x + pos_bwd[(q - (d0 + 0)) & (D - 1)];
    add.y = pf.y + pos_bwd[(q - (d0 + 1)) & (D - 1)];
    add.z = pf.z + pos_bwd[(q - (d0 + 2)) & (D - 1)];
    add.w = pf.w + pos_bwd[(q - (d0 + 3)) & (D - 1)];

    const f32x4* xg = reinterpret_cast<const f32x4*>(x) + (size_t)b * S * (D / 4) + dg;

    // ---- pass A: 16 loads; KEEP first 8 in regs, roll the rest ----
    f32x4 xr[KEEP];                   // 32 VGPRs, statically indexed
    #pragma unroll
    for (int i = 0; i < KEEP; ++i)
        xr[i] = xg[(s0 + i) * (D / 4)];

    f32x4 A = {0.f, 0.f, 0.f, 0.f};
    #pragma unroll
    for (int i = 0; i < KEEP; ++i) {
        A.x = fmaf(beta, A.x, xr[i].x);
        A.y = fmaf(beta, A.y, xr[i].y);
        A.z = fmaf(beta, A.z, xr[i].z);
        A.w = fmaf(beta, A.w, xr[i].w);
    }
    #pragma unroll
    for (int i = KEEP; i < CL; ++i) {
        const f32x4 v = xg[(s0 + i) * (D / 4)];
        A.x = fmaf(beta, A.x, v.x);
        A.y = fmaf(beta, A.y, v.y);
        A.z = fmaf(beta, A.z, v.z);
        A.w = fmaf(beta, A.w, v.w);
    }
    sA[c][dg] = A;
    __syncthreads();

    // ---- scan (8 threads, one per dg): exclusive carries over 64 chunks ----
    if (tid < D / 4) {
        f32x4 run = {0.f, 0.f, 0.f, 0.f};
        for (int cc = 0; cc < NCH; ++cc) {
            sC[cc][tid] = run;
            const f32x4 Ac = sA[cc][tid];
            f32x4 z;
            if (cc >= LAG) {
                const f32x4 Al = sA[cc - LAG][tid];
                z.x = alpha * fmaf(-bP, Al.x, Ac.x);
                z.y = alpha * fmaf(-bP, Al.y, Ac.y);
                z.z = alpha * fmaf(-bP, Al.z, Ac.z);
                z.w = alpha * fmaf(-bP, Al.w, Ac.w);
            } else {
                z.x = alpha * Ac.x; z.y = alpha * Ac.y;
                z.z = alpha * Ac.z; z.w = alpha * Ac.w;
            }
            run.x = fmaf(bCL, run.x, z.x);
            run.y = fmaf(bCL, run.y, z.y);
            run.z = fmaf(bCL, run.z, z.z);
            run.w = fmaf(bCL, run.w, z.w);
        }
    }
    __syncthreads();
    f32x4 y = sC[c][dg];

    // ---- pass B: first 8 outputs from kept regs (no post-barrier stall), ----
    // ---- last 8 re-read x (LLC-hit); lag via lockstep shfl in both halves ----
    f32x4* og = reinterpret_cast<f32x4*>(out) + ((size_t)b * S + s0) * (D / 4) + dg;
    #pragma unroll
    for (int i = 0; i < KEEP; ++i) {
        f32x4 o;
        o.x = y.x + add.x; o.y = y.y + add.y;
        o.z = y.z + add.z; o.w = y.w + add.w;
        __builtin_nontemporal_store(o, &og[i * (D / 4)]);

        f32x4 xl;
        xl.x = __shfl_up(xr[i].x, 8);
        xl.y = __shfl_up(xr[i].y, 8);
        xl.z = __shfl_up(xr[i].z, 8);
        xl.w = __shfl_up(xr[i].w, 8);

        y.x = fmaf(beta, y.x, fmaf(alpha, xr[i].x, m * xl.x));
        y.y = fmaf(beta, y.y, fmaf(alpha, xr[i].y, m * xl.y));
        y.z = fmaf(beta, y.z, fmaf(alpha, xr[i].z, m * xl.z));
        y.w = fmaf(beta, y.w, fmaf(alpha, xr[i].w, m * xl.w));
    }
    #pragma unroll
    for (int i = KEEP; i < CL; ++i) {
        const f32x4 xt = xg[(s0 + i) * (D / 4)];  // LLC-resident re-read

        f32x4 o;
        o.x = y.x + add.x; o.y = y.y + add.y;
        o.z = y.z + add.z; o.w = y.w + add.w;
        __builtin_nontemporal_store(o, &og[i * (D / 4)]);

        f32x4 xl;                     // lane g-1 loaded the same xt in lockstep
        xl.x = __shfl_up(xt.x, 8);
        xl.y = __shfl_up(xt.y, 8);
        xl.z = __shfl_up(xt.z, 8);
        xl.w = __shfl_up(xt.w, 8);

        y.x = fmaf(beta, y.x, fmaf(alpha, xt.x, m * xl.x));
        y.y = fmaf(beta, y.y, fmaf(alpha, xt.y, m * xl.y));
        y.z = fmaf(beta, y.z, fmaf(alpha, xt.z, m * xl.z));
        y.w = fmaf(beta, y.w, fmaf(alpha, xt.w, m * xl.w));
    }
}

extern "C" void kernel_launch(void* const* d_in, const int* in_sizes, int n_in,
                              void* d_out, int out_size, void* d_ws, size_t ws_size,
                              hipStream_t stream) {
    const float* x  = (const float*)d_in[0];
    const float* al = (const float*)d_in[1];
    const float* be = (const float*)d_in[2];
    const float* pf = (const float*)d_in[3];
    const float* pb = (const float*)d_in[4];
    const int*   ps = (const int*)d_in[5];
    float* out = (float*)d_out;

    const int B = in_sizes[0] / (S * D);   // 1024 rows, one block each -> 4 blocks/CU
    attn_pred_kernel<<<dim3(B), NTHR, 0, stream>>>(x, al, be, pf, pb, ps, out);
}